// Round 1
// baseline (207.430 us; speedup 1.0000x reference)
//
#include <hip/hip_runtime.h>

#define HW   262144   // 512*512
#define HW4  65536    // HW/4
#define NSEG 256
#define NB   8

// -------- Kernel 1: accumulate per-(batch,segment) moments ----------------
// acc[b][k][s], k: 0=count, 1..3=Sx_c, 4..6=Sx_c^2, 7=Sx0x1, 8=Sx0x2, 9=Sx1x2
__device__ __forceinline__ void accum_px(float* hist, int s,
                                         float x0, float x1, float x2) {
  atomicAdd(&hist[0 * NSEG + s], 1.0f);
  atomicAdd(&hist[1 * NSEG + s], x0);
  atomicAdd(&hist[2 * NSEG + s], x1);
  atomicAdd(&hist[3 * NSEG + s], x2);
  atomicAdd(&hist[4 * NSEG + s], x0 * x0);
  atomicAdd(&hist[5 * NSEG + s], x1 * x1);
  atomicAdd(&hist[6 * NSEG + s], x2 * x2);
  atomicAdd(&hist[7 * NSEG + s], x0 * x1);
  atomicAdd(&hist[8 * NSEG + s], x0 * x2);
  atomicAdd(&hist[9 * NSEG + s], x1 * x2);
}

__global__ __launch_bounds__(256) void k_accum(const float* __restrict__ x,
                                               const int* __restrict__ labels,
                                               float* __restrict__ acc) {
  __shared__ float hist[10 * NSEG];
  const int t = threadIdx.x;
  for (int i = t; i < 10 * NSEG; i += 256) hist[i] = 0.f;
  __syncthreads();

  const int b = blockIdx.x >> 7;        // 128 blocks per batch
  const int chunk = blockIdx.x & 127;   // 512 float4-groups per block
  const float4* __restrict__ x4 = (const float4*)(x + (size_t)b * 3 * HW);
  const int4*  __restrict__ l4  = (const int4*)(labels + (size_t)b * HW);

  #pragma unroll
  for (int i = 0; i < 2; ++i) {
    const int g = (chunk << 9) + (i << 8) + t;
    float4 a0 = x4[g];
    float4 a1 = x4[HW4 + g];
    float4 a2 = x4[2 * HW4 + g];
    int4  lb  = l4[g];
    accum_px(hist, lb.x, a0.x, a1.x, a2.x);
    accum_px(hist, lb.y, a0.y, a1.y, a2.y);
    accum_px(hist, lb.z, a0.z, a1.z, a2.z);
    accum_px(hist, lb.w, a0.w, a1.w, a2.w);
  }
  __syncthreads();

  float* ab = acc + b * (10 * NSEG);
  #pragma unroll
  for (int k = 0; k < 10; ++k)
    atomicAdd(&ab[k * NSEG + t], hist[k * NSEG + t]);
}

// -------- Kernel 2: moments -> mean/std -> reduce_conv -> L2 normalize ----
// block = 256 threads = 4 waves; each wave handles one (b,s) segment.
__global__ __launch_bounds__(256) void k_stats(const float* __restrict__ acc,
                                               const float* __restrict__ W_pix,
                                               const float* __restrict__ b_pix,
                                               const float* __restrict__ W_red,
                                               const float* __restrict__ b_red,
                                               float* __restrict__ rn) {
  __shared__ float wred[64 * 129];   // +1 pad: bank = (f+g)%32, conflict-free
  __shared__ float comb[4][132];
  const int t = threadIdx.x;

  // stage W_red (64x128) coalesced, padded stride 129
  for (int j4 = t; j4 < 2048; j4 += 256) {
    const int row = j4 >> 5;
    const int c4  = (j4 & 31) << 2;
    float4 v = ((const float4*)W_red)[j4];
    float* d = &wred[row * 129 + c4];
    d[0] = v.x; d[1] = v.y; d[2] = v.z; d[3] = v.w;
  }
  __syncthreads();

  const int w = t >> 6;        // wave in block
  const int f = t & 63;        // feature / lane
  const int seg = blockIdx.x * 4 + w;   // 0..2047
  const int b = seg >> 8;
  const int s = seg & 255;

  const float* a = acc + b * (10 * NSEG);
  const float N   = fmaxf(a[0 * NSEG + s], 1.0f);
  const float S0  = a[1 * NSEG + s];
  const float S1  = a[2 * NSEG + s];
  const float S2  = a[3 * NSEG + s];
  const float M00 = a[4 * NSEG + s];
  const float M11 = a[5 * NSEG + s];
  const float M22 = a[6 * NSEG + s];
  const float M01 = a[7 * NSEG + s];
  const float M02 = a[8 * NSEG + s];
  const float M12 = a[9 * NSEG + s];

  const float w0 = W_pix[f * 3 + 0];
  const float w1 = W_pix[f * 3 + 1];
  const float w2 = W_pix[f * 3 + 2];
  const float bf = b_pix[f];

  const float wS   = w0 * S0 + w1 * S1 + w2 * S2;
  const float mean = (wS + N * bf) / N;
  const float ssq  = w0 * w0 * M00 + w1 * w1 * M11 + w2 * w2 * M22
                   + 2.f * (w0 * w1 * M01 + w0 * w2 * M02 + w1 * w2 * M12)
                   + 2.f * bf * wS + N * bf * bf;
  const float var  = ssq / N - mean * mean;
  const float stdv = sqrtf(fmaxf(var, 1e-6f));

  comb[w][f]      = mean;
  comb[w][64 + f] = stdv;
  __syncthreads();

  float r = b_red[f];
  const float* wr = &wred[f * 129];
  const float* cb = comb[w];
  for (int g = 0; g < 128; ++g) r += wr[g] * cb[g];

  float sq = r * r;
  #pragma unroll
  for (int off = 32; off > 0; off >>= 1) sq += __shfl_xor(sq, off, 64);
  const float inv = 1.0f / fmaxf(sqrtf(sq), 1e-12f);

  rn[(size_t)seg * 64 + f] = r * inv;
}

// -------- Kernel 3: sim = rn rn^T, fused conv1x1 + BN(eval) + ReLU --------
__global__ __launch_bounds__(256) void k_sim(const float* __restrict__ rn,
                                             float* __restrict__ out,
                                             const float* __restrict__ w_sim,
                                             const float* __restrict__ b_sim,
                                             const float* __restrict__ bn_g,
                                             const float* __restrict__ bn_b,
                                             const float* __restrict__ bn_m,
                                             const float* __restrict__ bn_v) {
  __shared__ float A[64 * 65];
  __shared__ float Bt[64 * 65];
  const int t  = threadIdx.x;
  const int b  = blockIdx.x >> 4;
  const int ti = (blockIdx.x >> 2) & 3;
  const int tj = blockIdx.x & 3;

  const float4* rn4 = (const float4*)(rn + (size_t)b * NSEG * 64);
  for (int j4 = t; j4 < 1024; j4 += 256) {
    const int row = j4 >> 4;
    const int c4  = (j4 & 15) << 2;
    float4 va = rn4[(ti * 64 + row) * 16 + (j4 & 15)];
    float* da = &A[row * 65 + c4];
    da[0] = va.x; da[1] = va.y; da[2] = va.z; da[3] = va.w;
    float4 vb = rn4[(tj * 64 + row) * 16 + (j4 & 15)];
    float* db = &Bt[row * 65 + c4];
    db[0] = vb.x; db[1] = vb.y; db[2] = vb.z; db[3] = vb.w;
  }
  __syncthreads();

  const int tx = t & 15;
  const int ty = t >> 4;
  float acc[4][4] = {{0.f}};
  for (int k = 0; k < 64; ++k) {
    float av[4], bv[4];
    #pragma unroll
    for (int i = 0; i < 4; ++i) av[i] = A[(ty * 4 + i) * 65 + k];
    #pragma unroll
    for (int j = 0; j < 4; ++j) bv[j] = Bt[(tx * 4 + j) * 65 + k];
    #pragma unroll
    for (int i = 0; i < 4; ++i)
      #pragma unroll
      for (int j = 0; j < 4; ++j) acc[i][j] += av[i] * bv[j];
  }

  const float invsd = 1.0f / sqrtf(bn_v[0] + 1e-5f);
  const float scale = w_sim[0] * bn_g[0] * invsd;
  const float shift = (b_sim[0] - bn_m[0]) * bn_g[0] * invsd + bn_b[0];

  #pragma unroll
  for (int i = 0; i < 4; ++i) {
    float4 v;
    v.x = fmaxf(acc[i][0] * scale + shift, 0.f);
    v.y = fmaxf(acc[i][1] * scale + shift, 0.f);
    v.z = fmaxf(acc[i][2] * scale + shift, 0.f);
    v.w = fmaxf(acc[i][3] * scale + shift, 0.f);
    const int base = b * 65536 + (ti * 64 + ty * 4 + i) * 256 + tj * 64;
    ((float4*)out)[(base >> 2) + tx] = v;
  }
}

extern "C" void kernel_launch(void* const* d_in, const int* in_sizes, int n_in,
                              void* d_out, int out_size, void* d_ws, size_t ws_size,
                              hipStream_t stream) {
  (void)in_sizes; (void)n_in; (void)out_size; (void)ws_size;
  const float* x      = (const float*)d_in[0];
  const int*   labels = (const int*)d_in[1];
  // d_in[2] = num_spixels (256, hard-coded)
  const float* W_pix  = (const float*)d_in[3];
  const float* b_pix  = (const float*)d_in[4];
  const float* W_red  = (const float*)d_in[5];
  const float* b_red  = (const float*)d_in[6];
  const float* w_sim  = (const float*)d_in[7];
  const float* b_sim  = (const float*)d_in[8];
  const float* bn_g   = (const float*)d_in[9];
  const float* bn_b   = (const float*)d_in[10];
  const float* bn_m   = (const float*)d_in[11];
  const float* bn_v   = (const float*)d_in[12];
  float* out = (float*)d_out;

  float* acc = (float*)d_ws;                       // 8*10*256 floats = 80 KB
  float* rn  = (float*)d_ws + NB * 10 * NSEG;      // 8*256*64 floats = 512 KB

  hipMemsetAsync(acc, 0, NB * 10 * NSEG * sizeof(float), stream);
  k_accum<<<dim3(1024), dim3(256), 0, stream>>>(x, labels, acc);
  k_stats<<<dim3(512), dim3(256), 0, stream>>>(acc, W_pix, b_pix, W_red, b_red, rn);
  k_sim<<<dim3(128), dim3(256), 0, stream>>>(rn, out, w_sim, b_sim, bn_g, bn_b, bn_m, bn_v);
}